// Round 1
// baseline (224.223 us; speedup 1.0000x reference)
//
#include <hip/hip_runtime.h>
#include <hip/hip_bf16.h>

#define TEMP_INV (1.0f / 0.07f)
#define EPS 1e-12f

typedef __attribute__((ext_vector_type(4))) float f32x4;
typedef __attribute__((ext_vector_type(8))) short bf16x8;

// ---------------- Kernel A: L2-normalize rows, emit bf16 ----------------
__global__ void normalize_kernel(const float* __restrict__ feat,
                                 ushort* __restrict__ fb,
                                 int N, int D) {
    int wave = (blockIdx.x * blockDim.x + threadIdx.x) >> 6;
    int lane = threadIdx.x & 63;
    if (wave >= N) return;
    const float* row = feat + (size_t)wave * D;
    float s = 0.f;
    for (int k = lane; k < D; k += 64) { float v = row[k]; s += v * v; }
    #pragma unroll
    for (int off = 1; off < 64; off <<= 1) s += __shfl_xor(s, off);
    float scale = 1.0f / fmaxf(sqrtf(s), EPS);
    ushort* orow = fb + (size_t)wave * D;
    for (int k = lane; k < D; k += 64) {
        __hip_bfloat16 h = __float2bfloat16(row[k] * scale);
        orow[k] = *reinterpret_cast<ushort*>(&h);
    }
}

// ---------------- Kernel B: fused S = f f^T / T with per-row stats ------
// Block: 256 threads = 4 waves in 2x2; block tile 128x128; wave tile 64x64.
// mfma_f32_16x16x32_bf16:
//   A frag: lane l holds A[l&15][8*(l>>4)+i], i=0..7
//   B frag: lane l holds B[8*(l>>4)+i][l&15]  == f[l&15][...] since B = f^T
//   D frag: lane l reg i = D[(l>>4)*4+i][l&15]
__global__ __launch_bounds__(256) void supcon_main(
    const ushort* __restrict__ fb,
    const int* __restrict__ labels,
    float* __restrict__ denom, float* __restrict__ possum, float* __restrict__ pcnt,
    int N, int D) {

    const int tid  = threadIdx.x;
    const int lane = tid & 63;
    const int w    = tid >> 6;
    const int wr   = w >> 1, wc = w & 1;

    const int rowbase = blockIdx.y * 128 + wr * 64;
    const int colbase = blockIdx.x * 128 + wc * 64;

    const int r16 = lane & 15;
    const int kg8 = (lane >> 4) << 3;   // 0,8,16,24

    f32x4 acc[4][4];
    #pragma unroll
    for (int m = 0; m < 4; m++)
        #pragma unroll
        for (int n = 0; n < 4; n++)
            acc[m][n] = f32x4{0.f, 0.f, 0.f, 0.f};

    for (int k0 = 0; k0 < D; k0 += 32) {
        const int kk = k0 + kg8;
        bf16x8 a[4], b[4];
        #pragma unroll
        for (int m = 0; m < 4; m++) {
            int r = rowbase + m * 16 + r16;
            a[m] = *reinterpret_cast<const bf16x8*>(fb + (size_t)r * D + kk);
        }
        #pragma unroll
        for (int n = 0; n < 4; n++) {
            int c = colbase + n * 16 + r16;
            b[n] = *reinterpret_cast<const bf16x8*>(fb + (size_t)c * D + kk);
        }
        #pragma unroll
        for (int m = 0; m < 4; m++)
            #pragma unroll
            for (int n = 0; n < 4; n++)
                acc[m][n] = __builtin_amdgcn_mfma_f32_16x16x32_bf16(a[m], b[n], acc[m][n], 0, 0, 0);
    }

    // Epilogue: per-row partial {sum exp(sim), sum_pos sim, pos_count}
    #pragma unroll
    for (int m = 0; m < 4; m++) {
        const int rq = rowbase + m * 16 + ((lane >> 4) << 2); // first of this lane's 4 rows
        int rlab[4];
        #pragma unroll
        for (int i = 0; i < 4; i++) rlab[i] = labels[rq + i];

        float pd[4] = {0.f, 0.f, 0.f, 0.f};
        float ps[4] = {0.f, 0.f, 0.f, 0.f};
        float pc[4] = {0.f, 0.f, 0.f, 0.f};

        #pragma unroll
        for (int n = 0; n < 4; n++) {
            const int c = colbase + n * 16 + r16;
            const int clab = labels[c];
            #pragma unroll
            for (int i = 0; i < 4; i++) {
                const int r = rq + i;
                const float sim = acc[m][n][i] * TEMP_INV;
                if (r != c) {
                    pd[i] += __expf(sim);
                    if (rlab[i] == clab) { ps[i] += sim; pc[i] += 1.0f; }
                }
            }
        }

        // reduce over the 16 lanes of this lane-group (they share the same 4 rows)
        #pragma unroll
        for (int off = 1; off < 16; off <<= 1) {
            #pragma unroll
            for (int i = 0; i < 4; i++) {
                pd[i] += __shfl_xor(pd[i], off);
                ps[i] += __shfl_xor(ps[i], off);
                pc[i] += __shfl_xor(pc[i], off);
            }
        }
        if ((lane & 15) == 0) {
            #pragma unroll
            for (int i = 0; i < 4; i++) {
                atomicAdd(&denom[rq + i],  pd[i]);
                atomicAdd(&possum[rq + i], ps[i]);
                atomicAdd(&pcnt[rq + i],   pc[i]);
            }
        }
    }
}

// ---------------- Kernel C: per-row loss + mean -------------------------
__global__ void finalize_kernel(const float* __restrict__ denom,
                                const float* __restrict__ possum,
                                const float* __restrict__ pcnt,
                                float* __restrict__ out, int N) {
    __shared__ float sdata[8];
    float s = 0.f;
    for (int r = threadIdx.x; r < N; r += blockDim.x) {
        float d = denom[r], p = possum[r], c = pcnt[r];
        s += -(p - c * logf(d + EPS)) / (c + EPS);
    }
    #pragma unroll
    for (int off = 1; off < 64; off <<= 1) s += __shfl_xor(s, off);
    int wv = threadIdx.x >> 6;
    if ((threadIdx.x & 63) == 0) sdata[wv] = s;
    __syncthreads();
    if (threadIdx.x == 0) {
        float t = 0.f;
        int nw = (int)(blockDim.x >> 6);
        for (int i = 0; i < nw; i++) t += sdata[i];
        out[0] = t / (float)N;
    }
}

extern "C" void kernel_launch(void* const* d_in, const int* in_sizes, int n_in,
                              void* d_out, int out_size, void* d_ws, size_t ws_size,
                              hipStream_t stream) {
    const float* feat  = (const float*)d_in[0];
    const int* labels  = (const int*)d_in[1];
    const int N = in_sizes[1];
    const int D = in_sizes[0] / N;

    char* ws = (char*)d_ws;
    ushort* fb = (ushort*)ws;                       // N*D bf16
    size_t fbytes = (size_t)N * D * sizeof(ushort);
    float* denom  = (float*)(ws + fbytes);
    float* possum = denom + N;
    float* pcnt   = possum + N;

    hipMemsetAsync(denom, 0, 3 * (size_t)N * sizeof(float), stream);

    normalize_kernel<<<(N + 3) / 4, 256, 0, stream>>>(feat, fb, N, D);

    dim3 grid(N / 128, N / 128);
    supcon_main<<<grid, 256, 0, stream>>>(fb, labels, denom, possum, pcnt, N, D);

    finalize_kernel<<<1, 512, 0, stream>>>(denom, possum, pcnt, (float*)d_out, N);
}

// Round 2
// 148.719 us; speedup vs baseline: 1.5077x; 1.5077x over previous
//
#include <hip/hip_runtime.h>
#include <hip/hip_bf16.h>

#define TEMP_INV (1.0f / 0.07f)
#define EPS 1e-12f
// (1/0.07) * log2(e): exp(sim/T) == exp2(sim * C_EXP)
#define C_EXP 20.609929155556625f
#define NUM_CLASSES 16

typedef __attribute__((ext_vector_type(4))) float f32x4;
typedef __attribute__((ext_vector_type(8))) short bf16x8;

__device__ __forceinline__ float bf2f(ushort u) {
    unsigned int x = ((unsigned int)u) << 16;
    return __uint_as_float(x);
}

// ---------------- Kernel A: L2-normalize rows -> bf16, emit ||f_bf16||^2 ----
__global__ void normalize_kernel(const float* __restrict__ feat,
                                 ushort* __restrict__ fb,
                                 float* __restrict__ sq,
                                 int N, int D) {
    int wave = (blockIdx.x * blockDim.x + threadIdx.x) >> 6;
    int lane = threadIdx.x & 63;
    if (wave >= N) return;
    const float* row = feat + (size_t)wave * D;
    float s = 0.f;
    for (int k = lane; k < D; k += 64) { float v = row[k]; s += v * v; }
    #pragma unroll
    for (int off = 1; off < 64; off <<= 1) s += __shfl_xor(s, off);
    float scale = 1.0f / fmaxf(sqrtf(s), EPS);
    ushort* orow = fb + (size_t)wave * D;
    float q = 0.f;
    for (int k = lane; k < D; k += 64) {
        __hip_bfloat16 h = __float2bfloat16(row[k] * scale);
        ushort u = *reinterpret_cast<ushort*>(&h);
        orow[k] = u;
        float hv = bf2f(u);
        q += hv * hv;
    }
    #pragma unroll
    for (int off = 1; off < 64; off <<= 1) q += __shfl_xor(q, off);
    if (lane == 0) sq[wave] = q;
}

// ---------------- Kernel A2: per-class feature sums + counts ---------------
// grid = 128 blocks: class = bx & 15, row segment = bx >> 4 (8 segs).
__global__ void classsum_kernel(const ushort* __restrict__ fb,
                                const int* __restrict__ labels,
                                float* __restrict__ g,
                                float* __restrict__ cntf,
                                int N, int D) {
    const int c    = blockIdx.x & (NUM_CLASSES - 1);
    const int seg  = blockIdx.x >> 4;
    const int d    = threadIdx.x & 127;
    const int half = threadIdx.x >> 7;
    const int rows_per_seg = N >> 3;
    const int r0 = seg * rows_per_seg + half * (rows_per_seg >> 1);
    const int r1 = r0 + (rows_per_seg >> 1);
    float acc = 0.f;
    float cnt = 0.f;
    for (int r = r0; r < r1; r++) {
        if (labels[r] == c) {
            acc += bf2f(fb[(size_t)r * D + d]);
            if (d == 0) cnt += 1.f;
        }
    }
    atomicAdd(&g[c * D + d], acc);
    if (d == 0) atomicAdd(&cntf[c], cnt);
}

// ---------------- Kernel B: denom_i += sum_j exp(sim_ij) (full row) --------
// Block: 256 threads = 4 waves side-by-side in columns.
// Block tile: 64 rows x 1024 cols, processed as 4 steps of 64x256.
// grid = (N/1024, N/64). No labels, no diag check, no conditionals.
__global__ __launch_bounds__(256) void supcon_denom(
    const ushort* __restrict__ fb,
    float* __restrict__ denom, int N, int D) {

    const int tid  = threadIdx.x;
    const int lane = tid & 63;
    const int w    = tid >> 6;
    const int r16  = lane & 15;
    const int g4   = lane >> 4;       // 0..3
    const int kg8  = g4 << 3;         // 0,8,16,24

    const int rowbase   = blockIdx.y * 64;
    const int chunkbase = blockIdx.x * 1024;

    float pd[4][4];                   // [m][i] per-row partial exp-sums
    #pragma unroll
    for (int m = 0; m < 4; m++)
        #pragma unroll
        for (int i = 0; i < 4; i++) pd[m][i] = 0.f;

    for (int s = 0; s < 4; s++) {
        const int colbase = chunkbase + s * 256 + w * 64;

        f32x4 acc[4][4];
        #pragma unroll
        for (int m = 0; m < 4; m++)
            #pragma unroll
            for (int n = 0; n < 4; n++) acc[m][n] = f32x4{0.f, 0.f, 0.f, 0.f};

        for (int k0 = 0; k0 < D; k0 += 32) {
            const int kk = k0 + kg8;
            bf16x8 a[4], b[4];
            #pragma unroll
            for (int m = 0; m < 4; m++) {
                int r = rowbase + m * 16 + r16;
                a[m] = *reinterpret_cast<const bf16x8*>(fb + (size_t)r * D + kk);
            }
            #pragma unroll
            for (int n = 0; n < 4; n++) {
                int c = colbase + n * 16 + r16;
                b[n] = *reinterpret_cast<const bf16x8*>(fb + (size_t)c * D + kk);
            }
            #pragma unroll
            for (int m = 0; m < 4; m++)
                #pragma unroll
                for (int n = 0; n < 4; n++)
                    acc[m][n] = __builtin_amdgcn_mfma_f32_16x16x32_bf16(a[m], b[n], acc[m][n], 0, 0, 0);
        }

        #pragma unroll
        for (int m = 0; m < 4; m++)
            #pragma unroll
            for (int n = 0; n < 4; n++)
                #pragma unroll
                for (int i = 0; i < 4; i++)
                    pd[m][i] += __builtin_amdgcn_exp2f(acc[m][n][i] * C_EXP);
    }

    // reduce across the 16 lanes sharing the same rows
    #pragma unroll
    for (int off = 1; off < 16; off <<= 1)
        #pragma unroll
        for (int m = 0; m < 4; m++)
            #pragma unroll
            for (int i = 0; i < 4; i++)
                pd[m][i] += __shfl_xor(pd[m][i], off);

    if (r16 == 0) {
        #pragma unroll
        for (int m = 0; m < 4; m++)
            #pragma unroll
            for (int i = 0; i < 4; i++)
                atomicAdd(&denom[rowbase + m * 16 + g4 * 4 + i], pd[m][i]);
    }
}

// ---------------- Kernel C: per-row loss ------------------------------------
// One wave per row: dot(f_i, g_lab) -> possum; correct denom; row loss.
__global__ void rowloss_kernel(const ushort* __restrict__ fb,
                               const int* __restrict__ labels,
                               const float* __restrict__ denom,
                               const float* __restrict__ sq,
                               const float* __restrict__ g,
                               const float* __restrict__ cntf,
                               float* __restrict__ rowloss,
                               int N, int D) {
    int r    = (blockIdx.x * blockDim.x + threadIdx.x) >> 6;
    int lane = threadIdx.x & 63;
    if (r >= N) return;
    int lab = labels[r];
    const ushort* frow = fb + (size_t)r * D;
    const float*  grow = g + lab * D;
    float p = 0.f;
    for (int k = lane; k < D; k += 64) p += bf2f(frow[k]) * grow[k];
    #pragma unroll
    for (int off = 1; off < 64; off <<= 1) p += __shfl_xor(p, off);
    if (lane == 0) {
        float sqr    = sq[r];
        float possum = (p - sqr) * TEMP_INV;
        float cnt    = cntf[lab] - 1.0f;
        float dn     = denom[r] - __builtin_amdgcn_exp2f(sqr * C_EXP);
        rowloss[r]   = -(possum - cnt * logf(dn + EPS)) / (cnt + EPS);
    }
}

// ---------------- Kernel D: mean (deterministic single-block reduce) --------
__global__ void reduce_kernel(const float* __restrict__ rowloss,
                              float* __restrict__ out, int N) {
    __shared__ float sdata[16];
    float s = 0.f;
    for (int r = threadIdx.x; r < N; r += blockDim.x) s += rowloss[r];
    #pragma unroll
    for (int off = 1; off < 64; off <<= 1) s += __shfl_xor(s, off);
    int wv = threadIdx.x >> 6;
    if ((threadIdx.x & 63) == 0) sdata[wv] = s;
    __syncthreads();
    if (threadIdx.x == 0) {
        float t = 0.f;
        int nw = (int)(blockDim.x >> 6);
        for (int i = 0; i < nw; i++) t += sdata[i];
        out[0] = t / (float)N;
    }
}

extern "C" void kernel_launch(void* const* d_in, const int* in_sizes, int n_in,
                              void* d_out, int out_size, void* d_ws, size_t ws_size,
                              hipStream_t stream) {
    const float* feat = (const float*)d_in[0];
    const int* labels = (const int*)d_in[1];
    const int N = in_sizes[1];
    const int D = in_sizes[0] / N;

    char* ws = (char*)d_ws;
    ushort* fb = (ushort*)ws;                         // N*D bf16
    size_t off = (size_t)N * D * sizeof(ushort);
    // zeroed region: denom[N], g[16*D], cntf[16]  (contiguous)
    float* denom = (float*)(ws + off);  off += (size_t)N * sizeof(float);
    float* g     = (float*)(ws + off);  off += (size_t)NUM_CLASSES * D * sizeof(float);
    float* cntf  = (float*)(ws + off);  off += (size_t)NUM_CLASSES * sizeof(float);
    size_t zbytes = (size_t)(N + NUM_CLASSES * D + NUM_CLASSES) * sizeof(float);
    // written-unconditionally region: sq[N], rowloss[N]
    float* sq      = (float*)(ws + off); off += (size_t)N * sizeof(float);
    float* rowloss = (float*)(ws + off);

    hipMemsetAsync(denom, 0, zbytes, stream);

    normalize_kernel<<<(N + 3) / 4, 256, 0, stream>>>(feat, fb, sq, N, D);
    classsum_kernel<<<NUM_CLASSES * 8, 256, 0, stream>>>(fb, labels, g, cntf, N, D);

    dim3 grid(N / 1024, N / 64);
    supcon_denom<<<grid, 256, 0, stream>>>(fb, denom, N, D);

    rowloss_kernel<<<(N + 3) / 4, 256, 0, stream>>>(fb, labels, denom, sq, g, cntf, rowloss, N, D);
    reduce_kernel<<<1, 1024, 0, stream>>>(rowloss, (float*)d_out, N);
}

// Round 3
// 127.584 us; speedup vs baseline: 1.7575x; 1.1657x over previous
//
#include <hip/hip_runtime.h>
#include <hip/hip_bf16.h>

#define TEMP_INV (1.0f / 0.07f)
#define EPS 1e-12f
// (1/0.07) * log2(e): exp(sim/T) == exp2(sim * C_EXP)
#define C_EXP 20.609929155556625f
#define NUM_CLASSES 16
#define CS_BLOCKS 128

typedef __attribute__((ext_vector_type(4))) float f32x4;
typedef __attribute__((ext_vector_type(8))) short bf16x8;

__device__ __forceinline__ float bf2f(ushort u) {
    unsigned int x = ((unsigned int)u) << 16;
    return __uint_as_float(x);
}

// ---------------- Kernel A: L2-normalize rows -> bf16, emit ||f_bf16||^2 ----
__global__ void normalize_kernel(const float* __restrict__ feat,
                                 ushort* __restrict__ fb,
                                 float* __restrict__ sq,
                                 int N, int D) {
    int wave = (blockIdx.x * blockDim.x + threadIdx.x) >> 6;
    int lane = threadIdx.x & 63;
    if (wave >= N) return;
    const float* row = feat + (size_t)wave * D;
    float s = 0.f;
    for (int k = lane; k < D; k += 64) { float v = row[k]; s += v * v; }
    #pragma unroll
    for (int off = 1; off < 64; off <<= 1) s += __shfl_xor(s, off);
    float scale = 1.0f / fmaxf(sqrtf(s), EPS);
    ushort* orow = fb + (size_t)wave * D;
    float q = 0.f;
    for (int k = lane; k < D; k += 64) {
        __hip_bfloat16 h = __float2bfloat16(row[k] * scale);
        ushort u = *reinterpret_cast<ushort*>(&h);
        orow[k] = u;
        float hv = bf2f(u);
        q += hv * hv;
    }
    #pragma unroll
    for (int off = 1; off < 64; off <<= 1) q += __shfl_xor(q, off);
    if (lane == 0) sq[wave] = q;
}

// ---------------- Kernel A2: per-class feature sums + counts ---------------
// 128 blocks x 64 rows. Label is uniform per iteration -> scalar broadcast.
// Each thread owns LDS slot [half][class][col]: no atomics in the loop.
__global__ __launch_bounds__(256) void classsum_kernel(
    const ushort* __restrict__ fb,
    const int* __restrict__ labels,
    float* __restrict__ g,
    float* __restrict__ cntf,
    int N, int D) {
    __shared__ float lds[2][NUM_CLASSES][128];
    __shared__ float ldc[2][NUM_CLASSES];
    const int d    = threadIdx.x & 127;
    const int half = threadIdx.x >> 7;
    #pragma unroll
    for (int c = 0; c < NUM_CLASSES; c++) lds[half][c][d] = 0.f;
    if (d < NUM_CLASSES) ldc[half][d] = 0.f;
    __syncthreads();

    const int rows_per_block = N / CS_BLOCKS;      // 64
    const int half_rows = rows_per_block >> 1;     // 32
    const int r0 = blockIdx.x * rows_per_block + half * half_rows;
    for (int r = r0; r < r0 + half_rows; r++) {
        int lab = labels[r];
        lds[half][lab][d] += bf2f(fb[(size_t)r * D + d]);
        if (d == 0) ldc[half][lab] += 1.f;
    }
    __syncthreads();

    for (int c = half; c < NUM_CLASSES; c += 2)
        atomicAdd(&g[c * D + d], lds[0][c][d] + lds[1][c][d]);
    if (threadIdx.x < NUM_CLASSES)
        atomicAdd(&cntf[threadIdx.x], ldc[0][threadIdx.x] + ldc[1][threadIdx.x]);
}

// ---------------- Kernel B: denom_i += sum_j exp(sim_ij) (full row) --------
// Block: 256 threads = 4 waves side-by-side in columns.
// Block tile: 64 rows x 512 cols, processed as 2 steps of 64x256.
// grid = (N/512, N/64) = 2048 blocks -> 8 blocks/CU available.
__global__ __launch_bounds__(256, 4) void supcon_denom(
    const ushort* __restrict__ fb,
    float* __restrict__ denom, int N, int D) {

    const int tid  = threadIdx.x;
    const int lane = tid & 63;
    const int w    = tid >> 6;
    const int r16  = lane & 15;
    const int g4   = lane >> 4;       // 0..3
    const int kg8  = g4 << 3;         // 0,8,16,24

    const int rowbase   = blockIdx.y * 64;
    const int chunkbase = blockIdx.x * 512;

    float pd[4][4];                   // [m][i] per-row partial exp-sums
    #pragma unroll
    for (int m = 0; m < 4; m++)
        #pragma unroll
        for (int i = 0; i < 4; i++) pd[m][i] = 0.f;

    #pragma unroll
    for (int s = 0; s < 2; s++) {
        const int colbase = chunkbase + s * 256 + w * 64;

        f32x4 acc[4][4];
        #pragma unroll
        for (int m = 0; m < 4; m++)
            #pragma unroll
            for (int n = 0; n < 4; n++) acc[m][n] = f32x4{0.f, 0.f, 0.f, 0.f};

        for (int k0 = 0; k0 < D; k0 += 32) {
            const int kk = k0 + kg8;
            bf16x8 a[4], b[4];
            #pragma unroll
            for (int m = 0; m < 4; m++) {
                int r = rowbase + m * 16 + r16;
                a[m] = *reinterpret_cast<const bf16x8*>(fb + (size_t)r * D + kk);
            }
            #pragma unroll
            for (int n = 0; n < 4; n++) {
                int c = colbase + n * 16 + r16;
                b[n] = *reinterpret_cast<const bf16x8*>(fb + (size_t)c * D + kk);
            }
            #pragma unroll
            for (int m = 0; m < 4; m++)
                #pragma unroll
                for (int n = 0; n < 4; n++)
                    acc[m][n] = __builtin_amdgcn_mfma_f32_16x16x32_bf16(a[m], b[n], acc[m][n], 0, 0, 0);
        }

        #pragma unroll
        for (int m = 0; m < 4; m++)
            #pragma unroll
            for (int n = 0; n < 4; n++)
                #pragma unroll
                for (int i = 0; i < 4; i++)
                    pd[m][i] += __builtin_amdgcn_exp2f(acc[m][n][i] * C_EXP);
    }

    // reduce across the 16 lanes sharing the same rows
    #pragma unroll
    for (int off = 1; off < 16; off <<= 1)
        #pragma unroll
        for (int m = 0; m < 4; m++)
            #pragma unroll
            for (int i = 0; i < 4; i++)
                pd[m][i] += __shfl_xor(pd[m][i], off);

    if (r16 == 0) {
        #pragma unroll
        for (int m = 0; m < 4; m++)
            #pragma unroll
            for (int i = 0; i < 4; i++)
                atomicAdd(&denom[rowbase + m * 16 + g4 * 4 + i], pd[m][i]);
    }
}

// ---------------- Kernel C: per-row loss ------------------------------------
__global__ void rowloss_kernel(const ushort* __restrict__ fb,
                               const int* __restrict__ labels,
                               const float* __restrict__ denom,
                               const float* __restrict__ sq,
                               const float* __restrict__ g,
                               const float* __restrict__ cntf,
                               float* __restrict__ rowloss,
                               int N, int D) {
    int r    = (blockIdx.x * blockDim.x + threadIdx.x) >> 6;
    int lane = threadIdx.x & 63;
    if (r >= N) return;
    int lab = labels[r];
    const ushort* frow = fb + (size_t)r * D;
    const float*  grow = g + lab * D;
    float p = 0.f;
    for (int k = lane; k < D; k += 64) p += bf2f(frow[k]) * grow[k];
    #pragma unroll
    for (int off = 1; off < 64; off <<= 1) p += __shfl_xor(p, off);
    if (lane == 0) {
        float sqr    = sq[r];
        float possum = (p - sqr) * TEMP_INV;
        float cnt    = cntf[lab] - 1.0f;
        float dn     = denom[r] - __builtin_amdgcn_exp2f(sqr * C_EXP);
        rowloss[r]   = -(possum - cnt * logf(dn + EPS)) / (cnt + EPS);
    }
}

// ---------------- Kernel D: mean (deterministic single-block reduce) --------
__global__ void reduce_kernel(const float* __restrict__ rowloss,
                              float* __restrict__ out, int N) {
    __shared__ float sdata[16];
    float s = 0.f;
    for (int r = threadIdx.x; r < N; r += blockDim.x) s += rowloss[r];
    #pragma unroll
    for (int off = 1; off < 64; off <<= 1) s += __shfl_xor(s, off);
    int wv = threadIdx.x >> 6;
    if ((threadIdx.x & 63) == 0) sdata[wv] = s;
    __syncthreads();
    if (threadIdx.x == 0) {
        float t = 0.f;
        int nw = (int)(blockDim.x >> 6);
        for (int i = 0; i < nw; i++) t += sdata[i];
        out[0] = t / (float)N;
    }
}

extern "C" void kernel_launch(void* const* d_in, const int* in_sizes, int n_in,
                              void* d_out, int out_size, void* d_ws, size_t ws_size,
                              hipStream_t stream) {
    const float* feat = (const float*)d_in[0];
    const int* labels = (const int*)d_in[1];
    const int N = in_sizes[1];
    const int D = in_sizes[0] / N;

    char* ws = (char*)d_ws;
    ushort* fb = (ushort*)ws;                         // N*D bf16
    size_t off = (size_t)N * D * sizeof(ushort);
    // zeroed region: denom[N], g[16*D], cntf[16]  (contiguous)
    float* denom = (float*)(ws + off);  off += (size_t)N * sizeof(float);
    float* g     = (float*)(ws + off);  off += (size_t)NUM_CLASSES * D * sizeof(float);
    float* cntf  = (float*)(ws + off);  off += (size_t)NUM_CLASSES * sizeof(float);
    size_t zbytes = (size_t)(N + NUM_CLASSES * D + NUM_CLASSES) * sizeof(float);
    // written-unconditionally region: sq[N], rowloss[N]
    float* sq      = (float*)(ws + off); off += (size_t)N * sizeof(float);
    float* rowloss = (float*)(ws + off);

    hipMemsetAsync(denom, 0, zbytes, stream);

    normalize_kernel<<<(N + 3) / 4, 256, 0, stream>>>(feat, fb, sq, N, D);
    classsum_kernel<<<CS_BLOCKS, 256, 0, stream>>>(fb, labels, g, cntf, N, D);

    dim3 grid(N / 512, N / 64);
    supcon_denom<<<grid, 256, 0, stream>>>(fb, denom, N, D);

    rowloss_kernel<<<(N + 3) / 4, 256, 0, stream>>>(fb, labels, denom, sq, g, cntf, rowloss, N, D);
    reduce_kernel<<<1, 1024, 0, stream>>>(rowloss, (float*)d_out, N);
}

// Round 4
// 97.008 us; speedup vs baseline: 2.3114x; 1.3152x over previous
//
#include <hip/hip_runtime.h>
#include <hip/hip_bf16.h>

#define TEMP_INV (1.0f / 0.07f)
#define EPS 1e-12f
// (1/0.07) * log2(e): exp(sim/T) == exp2(sim * C_EXP)
#define C_EXP 20.609929155556625f
#define NUM_CLASSES 16
#define CS_BLOCKS 128

typedef __attribute__((ext_vector_type(4))) float f32x4;
typedef __attribute__((ext_vector_type(8))) short bf16x8;

__device__ __forceinline__ float bf2f(ushort u) {
    unsigned int x = ((unsigned int)u) << 16;
    return __uint_as_float(x);
}

// ---------------- Kernel A: L2-normalize rows -> bf16, emit ||f_bf16||^2 ----
__global__ void normalize_kernel(const float* __restrict__ feat,
                                 ushort* __restrict__ fb,
                                 float* __restrict__ sq,
                                 int N, int D) {
    int wave = (blockIdx.x * blockDim.x + threadIdx.x) >> 6;
    int lane = threadIdx.x & 63;
    if (wave >= N) return;
    const float* row = feat + (size_t)wave * D;
    float s = 0.f;
    for (int k = lane; k < D; k += 64) { float v = row[k]; s += v * v; }
    #pragma unroll
    for (int off = 1; off < 64; off <<= 1) s += __shfl_xor(s, off);
    float scale = 1.0f / fmaxf(sqrtf(s), EPS);
    ushort* orow = fb + (size_t)wave * D;
    float q = 0.f;
    for (int k = lane; k < D; k += 64) {
        __hip_bfloat16 h = __float2bfloat16(row[k] * scale);
        ushort u = *reinterpret_cast<ushort*>(&h);
        orow[k] = u;
        float hv = bf2f(u);
        q += hv * hv;
    }
    #pragma unroll
    for (int off = 1; off < 64; off <<= 1) q += __shfl_xor(q, off);
    if (lane == 0) sq[wave] = q;
}

// ---------------- Kernel A2: per-class feature sums + counts ---------------
// 128 blocks x 64 rows. Each thread owns LDS slot [half][class][col]:
// no atomics in the loop, coalesced row loads, uniform label broadcast.
__global__ __launch_bounds__(256) void classsum_kernel(
    const ushort* __restrict__ fb,
    const int* __restrict__ labels,
    float* __restrict__ g,
    float* __restrict__ cntf,
    int N, int D) {
    __shared__ float lds[2][NUM_CLASSES][128];
    __shared__ float ldc[2][NUM_CLASSES];
    const int d    = threadIdx.x & 127;
    const int half = threadIdx.x >> 7;
    #pragma unroll
    for (int c = 0; c < NUM_CLASSES; c++) lds[half][c][d] = 0.f;
    if (d < NUM_CLASSES) ldc[half][d] = 0.f;
    __syncthreads();

    const int rows_per_block = N / CS_BLOCKS;      // 64
    const int half_rows = rows_per_block >> 1;     // 32
    const int r0 = blockIdx.x * rows_per_block + half * half_rows;
    for (int r = r0; r < r0 + half_rows; r++) {
        int lab = labels[r];
        lds[half][lab][d] += bf2f(fb[(size_t)r * D + d]);
        if (d == 0) ldc[half][lab] += 1.f;
    }
    __syncthreads();

    for (int c = half; c < NUM_CLASSES; c += 2)
        atomicAdd(&g[c * D + d], lds[0][c][d] + lds[1][c][d]);
    if (threadIdx.x < NUM_CLASSES)
        atomicAdd(&cntf[threadIdx.x], ldc[0][threadIdx.x] + ldc[1][threadIdx.x]);
}

// ---------------- Kernel B: denom_i += sum_j exp(sim_ij) (full row) --------
// Block: 256 threads = 4 waves side-by-side in columns.
// Block tile: 64 rows x 512 cols (2 steps of 64x256); wave tile 64x64.
// A fragments (64 rows x K=128) are loaded ONCE into registers (64 VGPR)
// and reused for all column chunks. n-loop split in halves so only
// acc[4][2] (32 VGPR) is live at once -> no spill at 3 waves/SIMD.
__global__ __launch_bounds__(256, 3) void supcon_denom(
    const ushort* __restrict__ fb,
    float* __restrict__ denom, int N, int D) {

    const int tid  = threadIdx.x;
    const int lane = tid & 63;
    const int w    = tid >> 6;
    const int r16  = lane & 15;
    const int g4   = lane >> 4;       // 0..3
    const int kg8  = g4 << 3;         // 0,8,16,24

    const int rowbase   = blockIdx.y * 64;
    const int chunkbase = blockIdx.x * 512;

    // ---- A fragments for the whole K dimension, resident in registers ----
    bf16x8 a[4][4];                   // [ks][m]
    #pragma unroll
    for (int ks = 0; ks < 4; ks++) {
        const int kk = ks * 32 + kg8;
        #pragma unroll
        for (int m = 0; m < 4; m++) {
            int r = rowbase + m * 16 + r16;
            a[ks][m] = *reinterpret_cast<const bf16x8*>(fb + (size_t)r * D + kk);
        }
    }

    float pd[4][4];                   // [m][i] per-row partial exp-sums
    #pragma unroll
    for (int m = 0; m < 4; m++)
        #pragma unroll
        for (int i = 0; i < 4; i++) pd[m][i] = 0.f;

    #pragma unroll
    for (int s = 0; s < 2; s++) {
        const int colbase = chunkbase + s * 256 + w * 64;

        #pragma unroll
        for (int h = 0; h < 2; h++) {        // n-pair split: acc[4][2] live
            f32x4 acc[4][2];
            #pragma unroll
            for (int m = 0; m < 4; m++)
                #pragma unroll
                for (int n = 0; n < 2; n++) acc[m][n] = f32x4{0.f, 0.f, 0.f, 0.f};

            #pragma unroll
            for (int ks = 0; ks < 4; ks++) {
                const int kk = ks * 32 + kg8;
                bf16x8 b[2];
                #pragma unroll
                for (int n = 0; n < 2; n++) {
                    int c = colbase + (h * 2 + n) * 16 + r16;
                    b[n] = *reinterpret_cast<const bf16x8*>(fb + (size_t)c * D + kk);
                }
                #pragma unroll
                for (int m = 0; m < 4; m++)
                    #pragma unroll
                    for (int n = 0; n < 2; n++)
                        acc[m][n] = __builtin_amdgcn_mfma_f32_16x16x32_bf16(a[ks][m], b[n], acc[m][n], 0, 0, 0);
            }

            #pragma unroll
            for (int m = 0; m < 4; m++)
                #pragma unroll
                for (int n = 0; n < 2; n++)
                    #pragma unroll
                    for (int i = 0; i < 4; i++)
                        pd[m][i] += __builtin_amdgcn_exp2f(acc[m][n][i] * C_EXP);
        }
    }

    // reduce across the 16 lanes sharing the same rows
    #pragma unroll
    for (int off = 1; off < 16; off <<= 1)
        #pragma unroll
        for (int m = 0; m < 4; m++)
            #pragma unroll
            for (int i = 0; i < 4; i++)
                pd[m][i] += __shfl_xor(pd[m][i], off);

    if (r16 == 0) {
        #pragma unroll
        for (int m = 0; m < 4; m++)
            #pragma unroll
            for (int i = 0; i < 4; i++)
                atomicAdd(&denom[rowbase + m * 16 + g4 * 4 + i], pd[m][i]);
    }
}

// ---------------- Kernel C: per-row loss ------------------------------------
__global__ void rowloss_kernel(const ushort* __restrict__ fb,
                               const int* __restrict__ labels,
                               const float* __restrict__ denom,
                               const float* __restrict__ sq,
                               const float* __restrict__ g,
                               const float* __restrict__ cntf,
                               float* __restrict__ rowloss,
                               int N, int D) {
    int r    = (blockIdx.x * blockDim.x + threadIdx.x) >> 6;
    int lane = threadIdx.x & 63;
    if (r >= N) return;
    int lab = labels[r];
    const ushort* frow = fb + (size_t)r * D;
    const float*  grow = g + lab * D;
    float p = 0.f;
    for (int k = lane; k < D; k += 64) p += bf2f(frow[k]) * grow[k];
    #pragma unroll
    for (int off = 1; off < 64; off <<= 1) p += __shfl_xor(p, off);
    if (lane == 0) {
        float sqr    = sq[r];
        float possum = (p - sqr) * TEMP_INV;
        float cnt    = cntf[lab] - 1.0f;
        float dn     = denom[r] - __builtin_amdgcn_exp2f(sqr * C_EXP);
        rowloss[r]   = -(possum - cnt * logf(dn + EPS)) / (cnt + EPS);
    }
}

// ---------------- Kernel D: mean (deterministic single-block reduce) --------
__global__ void reduce_kernel(const float* __restrict__ rowloss,
                              float* __restrict__ out, int N) {
    __shared__ float sdata[16];
    float s = 0.f;
    for (int r = threadIdx.x; r < N; r += blockDim.x) s += rowloss[r];
    #pragma unroll
    for (int off = 1; off < 64; off <<= 1) s += __shfl_xor(s, off);
    int wv = threadIdx.x >> 6;
    if ((threadIdx.x & 63) == 0) sdata[wv] = s;
    __syncthreads();
    if (threadIdx.x == 0) {
        float t = 0.f;
        int nw = (int)(blockDim.x >> 6);
        for (int i = 0; i < nw; i++) t += sdata[i];
        out[0] = t / (float)N;
    }
}

extern "C" void kernel_launch(void* const* d_in, const int* in_sizes, int n_in,
                              void* d_out, int out_size, void* d_ws, size_t ws_size,
                              hipStream_t stream) {
    const float* feat = (const float*)d_in[0];
    const int* labels = (const int*)d_in[1];
    const int N = in_sizes[1];
    const int D = in_sizes[0] / N;

    char* ws = (char*)d_ws;
    ushort* fb = (ushort*)ws;                         // N*D bf16
    size_t off = (size_t)N * D * sizeof(ushort);
    // zeroed region: denom[N], g[16*D], cntf[16]  (contiguous)
    float* denom = (float*)(ws + off);  off += (size_t)N * sizeof(float);
    float* g     = (float*)(ws + off);  off += (size_t)NUM_CLASSES * D * sizeof(float);
    float* cntf  = (float*)(ws + off);  off += (size_t)NUM_CLASSES * sizeof(float);
    size_t zbytes = (size_t)(N + NUM_CLASSES * D + NUM_CLASSES) * sizeof(float);
    // written-unconditionally region: sq[N], rowloss[N]
    float* sq      = (float*)(ws + off); off += (size_t)N * sizeof(float);
    float* rowloss = (float*)(ws + off);

    hipMemsetAsync(denom, 0, zbytes, stream);

    normalize_kernel<<<(N + 3) / 4, 256, 0, stream>>>(feat, fb, sq, N, D);
    classsum_kernel<<<CS_BLOCKS, 256, 0, stream>>>(fb, labels, g, cntf, N, D);

    dim3 grid(N / 512, N / 64);
    supcon_denom<<<grid, 256, 0, stream>>>(fb, denom, N, D);

    rowloss_kernel<<<(N + 3) / 4, 256, 0, stream>>>(fb, labels, denom, sq, g, cntf, rowloss, N, D);
    reduce_kernel<<<1, 1024, 0, stream>>>(rowloss, (float*)d_out, N);
}

// Round 5
// 57.542 us; speedup vs baseline: 3.8967x; 1.6859x over previous
//
#include <hip/hip_runtime.h>
#include <hip/hip_bf16.h>

#define TEMP_INV (1.0f / 0.07f)
#define EPS 1e-12f
// (1/0.07) * log2(e): exp(sim/T) == exp2(sim * C_EXP)
#define C_EXP 20.609929155556625f
#define NUM_CLASSES 16
#define CS_BLOCKS 128

#define BM 256          // rows per block
#define BN 128          // cols per chunk
#define KD 128          // feature dim
#define NCHUNK 8        // col chunks per block (1024 cols)
#define NPART 16        // denom partials per row = colgroups(8) * wc(2)

typedef __attribute__((ext_vector_type(4))) float f32x4;
typedef __attribute__((ext_vector_type(8))) short bf16x8;

__device__ __forceinline__ float bf2f(ushort u) {
    unsigned int x = ((unsigned int)u) << 16;
    return __uint_as_float(x);
}

// Swizzled LDS fragment address: element (r, slot) of a [rows][128] bf16 tile,
// where slot indexes 16B chunks within the 256B row. Swizzle: slot ^= (r&7).
__device__ __forceinline__ const bf16x8* lds_frag(const ushort* base, int r, int slot) {
    int sw = slot ^ (r & 7);
    return reinterpret_cast<const bf16x8*>(
        reinterpret_cast<const char*>(base) + r * 256 + sw * 16);
}

// ---------------- Kernel A: L2-normalize rows -> bf16, emit ||f_bf16||^2 ----
__global__ void normalize_kernel(const float* __restrict__ feat,
                                 ushort* __restrict__ fb,
                                 float* __restrict__ sq,
                                 int N, int D) {
    int wave = (blockIdx.x * blockDim.x + threadIdx.x) >> 6;
    int lane = threadIdx.x & 63;
    if (wave >= N) return;
    const float* row = feat + (size_t)wave * D;
    float s = 0.f;
    for (int k = lane; k < D; k += 64) { float v = row[k]; s += v * v; }
    #pragma unroll
    for (int off = 1; off < 64; off <<= 1) s += __shfl_xor(s, off);
    float scale = 1.0f / fmaxf(sqrtf(s), EPS);
    ushort* orow = fb + (size_t)wave * D;
    float q = 0.f;
    for (int k = lane; k < D; k += 64) {
        __hip_bfloat16 h = __float2bfloat16(row[k] * scale);
        ushort u = *reinterpret_cast<ushort*>(&h);
        orow[k] = u;
        float hv = bf2f(u);
        q += hv * hv;
    }
    #pragma unroll
    for (int off = 1; off < 64; off <<= 1) q += __shfl_xor(q, off);
    if (lane == 0) sq[wave] = q;
}

// ---------------- Kernel A2: per-class feature sums + counts ---------------
__global__ __launch_bounds__(256) void classsum_kernel(
    const ushort* __restrict__ fb,
    const int* __restrict__ labels,
    float* __restrict__ g,
    float* __restrict__ cntf,
    int N, int D) {
    __shared__ float lds[2][NUM_CLASSES][128];
    __shared__ float ldc[2][NUM_CLASSES];
    const int d    = threadIdx.x & 127;
    const int half = threadIdx.x >> 7;
    #pragma unroll
    for (int c = 0; c < NUM_CLASSES; c++) lds[half][c][d] = 0.f;
    if (d < NUM_CLASSES) ldc[half][d] = 0.f;
    __syncthreads();

    const int rows_per_block = N / CS_BLOCKS;      // 64
    const int half_rows = rows_per_block >> 1;     // 32
    const int r0 = blockIdx.x * rows_per_block + half * half_rows;
    for (int r = r0; r < r0 + half_rows; r++) {
        int lab = labels[r];
        lds[half][lab][d] += bf2f(fb[(size_t)r * D + d]);
        if (d == 0) ldc[half][lab] += 1.f;
    }
    __syncthreads();

    for (int c = half; c < NUM_CLASSES; c += 2)
        atomicAdd(&g[c * D + d], lds[0][c][d] + lds[1][c][d]);
    if (threadIdx.x < NUM_CLASSES)
        atomicAdd(&cntf[threadIdx.x], ldc[0][threadIdx.x] + ldc[1][threadIdx.x]);
}

// ---------------- Kernel B: denom partials via persistent LDS-staged tiles --
// 256 blocks (grid 8 colgroups x 32 rowblocks), 512 threads = 8 waves (4x2).
// Block: stage A tile (256x128, 64KB) once; loop 8 col-chunks of 128 with
// double-buffered B tile (2x32KB). XOR-swizzled LDS layout, one barrier/chunk.
// Each (colgroup, wc) writes its own partial: denom_part[r*16 + part].
__global__ __launch_bounds__(512, 2) void supcon_denom(
    const ushort* __restrict__ fb,
    float* __restrict__ denom_part,
    int N, int D) {

    __shared__ __align__(16) ushort As[BM * KD];        // 64 KB
    __shared__ __align__(16) ushort Bs[2][BN * KD];     // 2 x 32 KB

    const int tid  = threadIdx.x;
    const int lane = tid & 63;
    const int w    = tid >> 6;        // 0..7
    const int wr   = w >> 1;          // 0..3  (row quadrant, 64 rows)
    const int wc   = w & 1;           // 0..1  (col half, 64 cols)
    const int r16  = lane & 15;
    const int g4   = lane >> 4;       // 0..3

    const int rowbase = blockIdx.y * BM;
    const int col0    = blockIdx.x * (BN * NCHUNK);

    // ---- stage A tile (rows rowbase..rowbase+255, contiguous 64KB) ----
    {
        const ushort* gA = fb + (size_t)rowbase * KD;
        #pragma unroll
        for (int i = 0; i < 8; i++) {
            int c = i * 512 + tid;                  // 16B chunk index
            bf16x8 v = *reinterpret_cast<const bf16x8*>(gA + c * 8);
            int dst = c ^ ((c >> 4) & 7);
            *reinterpret_cast<bf16x8*>(&As[dst * 8]) = v;
        }
        // stage B chunk 0 into buffer 0
        const ushort* gB = fb + (size_t)col0 * KD;
        #pragma unroll
        for (int i = 0; i < 4; i++) {
            int c = i * 512 + tid;
            bf16x8 v = *reinterpret_cast<const bf16x8*>(gB + c * 8);
            int dst = c ^ ((c >> 4) & 7);
            *reinterpret_cast<bf16x8*>(&Bs[0][dst * 8]) = v;
        }
    }
    __syncthreads();

    float pd[4][4];                   // [m][i] per-row exp-sum partials
    #pragma unroll
    for (int m = 0; m < 4; m++)
        #pragma unroll
        for (int i = 0; i < 4; i++) pd[m][i] = 0.f;

    int cur = 0;
    for (int c = 0; c < NCHUNK; c++) {
        // ---- issue next-chunk global loads early (latency hides under MFMA)
        bf16x8 pre0, pre1, pre2, pre3;
        if (c + 1 < NCHUNK) {
            const ushort* gB = fb + (size_t)(col0 + (c + 1) * BN) * KD;
            pre0 = *reinterpret_cast<const bf16x8*>(gB + (0 * 512 + tid) * 8);
            pre1 = *reinterpret_cast<const bf16x8*>(gB + (1 * 512 + tid) * 8);
            pre2 = *reinterpret_cast<const bf16x8*>(gB + (2 * 512 + tid) * 8);
            pre3 = *reinterpret_cast<const bf16x8*>(gB + (3 * 512 + tid) * 8);
        }

        // ---- compute 256x128 tile from LDS ----
        f32x4 acc[4][4];
        #pragma unroll
        for (int m = 0; m < 4; m++)
            #pragma unroll
            for (int n = 0; n < 4; n++) acc[m][n] = f32x4{0.f, 0.f, 0.f, 0.f};

        const ushort* bbase = Bs[cur];
        #pragma unroll
        for (int ks = 0; ks < 4; ks++) {
            const int slot = ks * 4 + g4;
            bf16x8 av[4], bv[4];
            #pragma unroll
            for (int m = 0; m < 4; m++)
                av[m] = *lds_frag(As, wr * 64 + m * 16 + r16, slot);
            #pragma unroll
            for (int n = 0; n < 4; n++)
                bv[n] = *lds_frag(bbase, wc * 64 + n * 16 + r16, slot);
            #pragma unroll
            for (int m = 0; m < 4; m++)
                #pragma unroll
                for (int n = 0; n < 4; n++)
                    acc[m][n] = __builtin_amdgcn_mfma_f32_16x16x32_bf16(av[m], bv[n], acc[m][n], 0, 0, 0);
        }

        #pragma unroll
        for (int m = 0; m < 4; m++)
            #pragma unroll
            for (int n = 0; n < 4; n++)
                #pragma unroll
                for (int i = 0; i < 4; i++)
                    pd[m][i] += __builtin_amdgcn_exp2f(acc[m][n][i] * C_EXP);

        // ---- write prefetched B into the other buffer, then publish ----
        if (c + 1 < NCHUNK) {
            ushort* dstb = Bs[cur ^ 1];
            int ch;
            ch = 0 * 512 + tid; *reinterpret_cast<bf16x8*>(&dstb[(ch ^ ((ch >> 4) & 7)) * 8]) = pre0;
            ch = 1 * 512 + tid; *reinterpret_cast<bf16x8*>(&dstb[(ch ^ ((ch >> 4) & 7)) * 8]) = pre1;
            ch = 2 * 512 + tid; *reinterpret_cast<bf16x8*>(&dstb[(ch ^ ((ch >> 4) & 7)) * 8]) = pre2;
            ch = 3 * 512 + tid; *reinterpret_cast<bf16x8*>(&dstb[(ch ^ ((ch >> 4) & 7)) * 8]) = pre3;
        }
        __syncthreads();
        cur ^= 1;
    }

    // ---- reduce across the 16 lanes sharing the same rows, write partials --
    #pragma unroll
    for (int off = 1; off < 16; off <<= 1)
        #pragma unroll
        for (int m = 0; m < 4; m++)
            #pragma unroll
            for (int i = 0; i < 4; i++)
                pd[m][i] += __shfl_xor(pd[m][i], off);

    if (r16 == 0) {
        const int part = blockIdx.x * 2 + wc;   // 0..15
        #pragma unroll
        for (int m = 0; m < 4; m++)
            #pragma unroll
            for (int i = 0; i < 4; i++) {
                int r = rowbase + wr * 64 + m * 16 + g4 * 4 + i;
                denom_part[(size_t)r * NPART + part] = pd[m][i];
            }
    }
}

// ---------------- Kernel C: per-row loss ------------------------------------
__global__ void rowloss_kernel(const ushort* __restrict__ fb,
                               const int* __restrict__ labels,
                               const float* __restrict__ denom_part,
                               const float* __restrict__ sq,
                               const float* __restrict__ g,
                               const float* __restrict__ cntf,
                               float* __restrict__ rowloss,
                               int N, int D) {
    int r    = (blockIdx.x * blockDim.x + threadIdx.x) >> 6;
    int lane = threadIdx.x & 63;
    if (r >= N) return;
    int lab = labels[r];
    const ushort* frow = fb + (size_t)r * D;
    const float*  grow = g + lab * D;
    float p = 0.f;
    for (int k = lane; k < D; k += 64) p += bf2f(frow[k]) * grow[k];
    #pragma unroll
    for (int off = 1; off < 64; off <<= 1) p += __shfl_xor(p, off);

    float dsum = (lane < NPART) ? denom_part[(size_t)r * NPART + lane] : 0.f;
    #pragma unroll
    for (int off = 1; off < NPART; off <<= 1) dsum += __shfl_xor(dsum, off);

    if (lane == 0) {
        float sqr    = sq[r];
        float possum = (p - sqr) * TEMP_INV;
        float cnt    = cntf[lab] - 1.0f;
        float dn     = dsum - __builtin_amdgcn_exp2f(sqr * C_EXP);
        rowloss[r]   = -(possum - cnt * logf(dn + EPS)) / (cnt + EPS);
    }
}

// ---------------- Kernel D: mean (deterministic single-block reduce) --------
__global__ void reduce_kernel(const float* __restrict__ rowloss,
                              float* __restrict__ out, int N) {
    __shared__ float sdata[16];
    float s = 0.f;
    for (int r = threadIdx.x; r < N; r += blockDim.x) s += rowloss[r];
    #pragma unroll
    for (int off = 1; off < 64; off <<= 1) s += __shfl_xor(s, off);
    int wv = threadIdx.x >> 6;
    if ((threadIdx.x & 63) == 0) sdata[wv] = s;
    __syncthreads();
    if (threadIdx.x == 0) {
        float t = 0.f;
        int nw = (int)(blockDim.x >> 6);
        for (int i = 0; i < nw; i++) t += sdata[i];
        out[0] = t / (float)N;
    }
}

extern "C" void kernel_launch(void* const* d_in, const int* in_sizes, int n_in,
                              void* d_out, int out_size, void* d_ws, size_t ws_size,
                              hipStream_t stream) {
    const float* feat = (const float*)d_in[0];
    const int* labels = (const int*)d_in[1];
    const int N = in_sizes[1];
    const int D = in_sizes[0] / N;

    char* ws = (char*)d_ws;
    ushort* fb = (ushort*)ws;                         // N*D bf16
    size_t off = (size_t)N * D * sizeof(ushort);
    // zeroed region: g[16*D], cntf[16] (contiguous)
    float* g     = (float*)(ws + off);  off += (size_t)NUM_CLASSES * D * sizeof(float);
    float* cntf  = (float*)(ws + off);  off += (size_t)NUM_CLASSES * sizeof(float);
    size_t zbytes = (size_t)(NUM_CLASSES * D + NUM_CLASSES) * sizeof(float);
    // written-unconditionally: sq[N], rowloss[N], denom_part[N*16]
    float* sq         = (float*)(ws + off); off += (size_t)N * sizeof(float);
    float* rowloss    = (float*)(ws + off); off += (size_t)N * sizeof(float);
    float* denom_part = (float*)(ws + off);

    hipMemsetAsync(g, 0, zbytes, stream);

    normalize_kernel<<<(N + 3) / 4, 256, 0, stream>>>(feat, fb, sq, N, D);
    classsum_kernel<<<CS_BLOCKS, 256, 0, stream>>>(fb, labels, g, cntf, N, D);

    dim3 grid(N / (BN * NCHUNK), N / BM);             // (8, 32) = 256 blocks
    supcon_denom<<<grid, 512, 0, stream>>>(fb, denom_part, N, D);

    rowloss_kernel<<<(N + 3) / 4, 256, 0, stream>>>(fb, labels, denom_part, sq, g, cntf, rowloss, N, D);
    reduce_kernel<<<1, 1024, 0, stream>>>(rowloss, (float*)d_out, N);
}